// Round 1
// baseline (528.729 us; speedup 1.0000x reference)
//
#include <hip/hip_runtime.h>
#include <hip/hip_bf16.h>

#define NC     80
#define BATCH  1048576
#define CHUNKS (BATCH / 32)          // 32768 K-chunks of 32 rows
#define NBLK   1024
#define NTHR   256
#define NWAVES (NBLK * NTHR / 64)    // 4096 waves, 8 chunks/wave
#define NTILE  15                    // upper-triangle 16x16 tiles of 80x80
#define CELLS  (NTILE * 256)         // 3840 partial cells per block

using bf16x8 = __attribute__((ext_vector_type(8))) __bf16;
using f32x4  = __attribute__((ext_vector_type(4))) float;

// Stage 1: G = label^T @ label (upper-triangle 16x16 tiles), bf16 MFMA.
// Labels are exactly {0,1} -> bf16 truncation is exact; all partial sums are
// integers < 2^24 -> fp32 accumulation is exact & order-independent.
// Epilogue: per-block partials written coalesced to workspace (NO global
// atomics -- the 1024-way same-address atomic serialization was the theory'd
// tail cost of the previous version).
__global__ __launch_bounds__(NTHR, 3) void gram_kernel(const float* __restrict__ label,
                                                       float* __restrict__ part) {
    __shared__ float Gs[NC * NC];
    const int tid = threadIdx.x;
    for (int u = tid; u < NC * NC; u += NTHR) Gs[u] = 0.0f;

    const int lane = tid & 63;
    const int m    = lane & 15;   // class-within-tile (output col / frag row)
    const int quad = lane >> 4;   // k-subchunk selector

    const int wid = (blockIdx.x * NTHR + tid) >> 6;   // global wave id

    f32x4 acc[NTILE];
#pragma unroll
    for (int t = 0; t < NTILE; ++t) acc[t] = (f32x4){0.f, 0.f, 0.f, 0.f};

    for (int c = wid; c < CHUNKS; c += NWAVES) {
        // lane reads 8 fp32 per fragment: rows kbase+quad*8+j, col 16t+m.
        // Rows are 320 B = 5 aligned 64B lines; each line fetched exactly once.
        const float* base = label + (size_t)(c * 32 + quad * 8) * NC + m;
        float v[8][5];
#pragma unroll
        for (int j = 0; j < 8; ++j) {
            const float* rp = base + j * NC;
#pragma unroll
            for (int t = 0; t < 5; ++t) v[j][t] = rp[t * 16];
        }

        // fp32 -> bf16 by top-16-bit truncation (exact for 0.0 / 1.0).
        // v_perm_b32 packs both high halves in ONE VALU op:
        //   dst = [hi.b3 hi.b2 lo.b3 lo.b2]  (sel 0x07060302, a=hi, b=lo)
        bf16x8 frag[5];
#pragma unroll
        for (int t = 0; t < 5; ++t) {
            union { unsigned int u[4]; bf16x8 b; } cv;
#pragma unroll
            for (int p = 0; p < 4; ++p)
                cv.u[p] = __builtin_amdgcn_perm(__float_as_uint(v[2 * p + 1][t]),
                                                __float_as_uint(v[2 * p][t]),
                                                0x07060302u);
            frag[t] = cv.b;
        }

        // G tile (ti,tj) = frag[ti]^T-as-A x frag[tj]-as-B ; upper triangle only
        int idx = 0;
#pragma unroll
        for (int ti = 0; ti < 5; ++ti)
#pragma unroll
            for (int tj = ti; tj < 5; ++tj) {
                acc[idx] = __builtin_amdgcn_mfma_f32_16x16x32_bf16(
                    frag[ti], frag[tj], acc[idx], 0, 0, 0);
                ++idx;
            }
    }

    __syncthreads();   // Gs zero-init complete across all waves

    // wave accs -> LDS (C/D layout: col = lane&15, row = quad*4 + reg)
    {
        int idx = 0;
#pragma unroll
        for (int ti = 0; ti < 5; ++ti)
#pragma unroll
            for (int tj = ti; tj < 5; ++tj) {
#pragma unroll
                for (int r = 0; r < 4; ++r) {
                    int row = 16 * ti + quad * 4 + r;
                    int col = 16 * tj + m;
                    atomicAdd(&Gs[row * NC + col], acc[idx][r]);
                }
                ++idx;
            }
    }
    __syncthreads();

    // block partial -> workspace, fully coalesced, no atomics.
    // cell layout: part[block*3840 + tile_idx*256 + tid]
    {
        const size_t base = (size_t)blockIdx.x * CELLS;
        const int r  = tid >> 4;
        const int cl = tid & 15;
        int idx = 0;
#pragma unroll
        for (int ti = 0; ti < 5; ++ti)
#pragma unroll
            for (int tj = ti; tj < 5; ++tj) {
                part[base + idx * 256 + tid] = Gs[(16 * ti + r) * NC + 16 * tj + cl];
                ++idx;
            }
    }
}

// Stage 1.5: fold 1024 block-partials into G. grid (15 tiles, 8 partial-ranges).
// Reads are fully coalesced (consecutive tid -> consecutive addresses);
// only 8 atomics per G cell (one per blockIdx.y) -- negligible contention.
__global__ __launch_bounds__(256) void reduce_kernel(const float* __restrict__ part,
                                                     float* __restrict__ G) {
    const int tid  = threadIdx.x;
    const int tile = blockIdx.x;                 // 0..14
    const int p0   = blockIdx.y * (NBLK / 8);    // 128 partials per block
    const int c    = tile * 256 + tid;

    float sum = 0.f;
#pragma unroll 4
    for (int p = 0; p < NBLK / 8; ++p)
        sum += part[(size_t)(p0 + p) * CELLS + c];

    // tile enumeration must match gram's (ti outer, tj >= ti inner)
    static const unsigned char TI[NTILE] = {0,0,0,0,0,1,1,1,1,2,2,2,3,3,4};
    static const unsigned char TJ[NTILE] = {0,1,2,3,4,1,2,3,4,2,3,4,3,4,4};
    const int row = 16 * TI[tile] + (tid >> 4);
    const int col = 16 * TJ[tile] + (tid & 15);
    atomicAdd(&G[row * NC + col], sum);
}

// Stage 2: target = cooc/(count+eps) + eye ; smooth-L1-ish ; mean -> out[0]
__global__ __launch_bounds__(256) void loss_kernel(const float* __restrict__ pre_adj,
                                                   const float* __restrict__ G,
                                                   float* __restrict__ out) {
    const int tid = threadIdx.x;
    float sum = 0.f;
    for (int u = tid; u < NC * NC; u += 256) {
        int i = u / NC, j = u - i * NC;
        float target;
        if (i == j) {
            target = 1.0f;
        } else {
            // G stored only for tile(i) <= tile(j); G is symmetric
            float num = ((i >> 4) <= (j >> 4)) ? G[i * NC + j] : G[j * NC + i];
            float cnt = G[i * NC + i];            // count[i] = diag (binary labels)
            target = num / (cnt + 1e-7f);
        }
        float r = fabsf(pre_adj[u] - target);
        sum += (r < 1.0f) ? r * r : (r - 0.5f);
    }
    // wave reduce (64 lanes) then cross-wave via LDS
#pragma unroll
    for (int off = 32; off > 0; off >>= 1) sum += __shfl_down(sum, off);
    __shared__ float ws[4];
    if ((tid & 63) == 0) ws[tid >> 6] = sum;
    __syncthreads();
    if (tid == 0) out[0] = (ws[0] + ws[1] + ws[2] + ws[3]) * (1.0f / 6400.0f);
}

extern "C" void kernel_launch(void* const* d_in, const int* in_sizes, int n_in,
                              void* d_out, int out_size, void* d_ws, size_t ws_size,
                              hipStream_t stream) {
    const float* pre_adj = (const float*)d_in[0];   // [80,80]
    const float* label   = (const float*)d_in[1];   // [1048576,80]
    float* out  = (float*)d_out;                    // scalar
    float* G    = (float*)d_ws;                     // 80*80 fp32 result
    float* part = G + NC * NC;                      // 1024 x 3840 block partials

    hipMemsetAsync(G, 0, NC * NC * sizeof(float), stream);
    gram_kernel<<<NBLK, NTHR, 0, stream>>>(label, part);
    reduce_kernel<<<dim3(NTILE, 8), 256, 0, stream>>>(part, G);
    loss_kernel<<<1, 256, 0, stream>>>(pre_adj, G, out);
}

// Round 2
// 527.453 us; speedup vs baseline: 1.0024x; 1.0024x over previous
//
#include <hip/hip_runtime.h>
#include <hip/hip_bf16.h>

#define NC     80
#define BATCH  1048576
#define CHUNKS (BATCH / 32)          // 32768 K-chunks of 32 rows
#define NBLK   1024
#define NTHR   256
#define NWAVES (NBLK * NTHR / 64)    // 4096 waves, 8 chunks/wave
#define NTILE  15                    // upper-triangle 16x16 tiles of 80x80

using bf16x8 = __attribute__((ext_vector_type(8))) __bf16;
using f32x4  = __attribute__((ext_vector_type(4))) float;

// Stage 1: G = label^T @ label (upper-triangle 16x16 tiles), bf16 MFMA.
// Labels are exactly {0,1} -> bf16 truncation is exact; all partial sums are
// integers < 2^24 -> fp32 atomicAdd accumulation is exact & order-independent.
//
// R1 lesson: global-atomic epilogue is CHEAP (partial-buffer split regressed
// +19us) -- reverted to direct atomics.
// R2 theory: occupancy. Without a min-waves bound the loop's live set
// (60 acc + 40 staging + 20 frag) exceeds 128 VGPRs -> 2-3 blocks/CU -> the
// 1024-block grid runs in two scheduling phases (straggler tail over the
// 53us streaming floor). Fix: pairwise load/convert keeps only 10 staging
// floats live (~100 VGPR total) + __launch_bounds__(256,4) pins 4 blocks/CU.
__global__ __launch_bounds__(NTHR, 4) void gram_kernel(const float* __restrict__ label,
                                                       float* __restrict__ G) {
    __shared__ float Gs[NC * NC];
    const int tid = threadIdx.x;
    for (int u = tid; u < NC * NC; u += NTHR) Gs[u] = 0.0f;

    const int lane = tid & 63;
    const int m    = lane & 15;   // class-within-tile (output col / frag row)
    const int quad = lane >> 4;   // k-subchunk selector

    const int wid = (blockIdx.x * NTHR + tid) >> 6;   // global wave id

    f32x4 acc[NTILE];
#pragma unroll
    for (int t = 0; t < NTILE; ++t) acc[t] = (f32x4){0.f, 0.f, 0.f, 0.f};

    union Frag { unsigned int u[4]; bf16x8 b; };

    for (int c = wid; c < CHUNKS; c += NWAVES) {
        // lane covers rows kbase+quad*8 .. +7, cols m+16t (t=0..4).
        // Each 320 B row = 5 aligned 64 B lines, each fetched exactly once
        // across the 16 lanes sharing a quad.
        const float* base = label + (size_t)(c * 32 + quad * 8) * NC + m;

        Frag fr[5];
        // Row-PAIR at a time: only 10 staging floats live (reg pressure!).
        // fp32 -> bf16 via top-16-bit truncation (exact for 0.0/1.0);
        // v_perm_b32 packs both halves in one VALU op.
#pragma unroll
        for (int p = 0; p < 4; ++p) {
            const float* rp = base + (2 * p) * NC;
            float a[5], b[5];
#pragma unroll
            for (int t = 0; t < 5; ++t) {
                a[t] = rp[t * 16];
                b[t] = rp[NC + t * 16];
            }
#pragma unroll
            for (int t = 0; t < 5; ++t)
                fr[t].u[p] = __builtin_amdgcn_perm(__float_as_uint(b[t]),
                                                   __float_as_uint(a[t]),
                                                   0x07060302u);
        }

        // G tile (ti,tj) = fr[ti]-as-A x fr[tj]-as-B ; upper triangle only
        int idx = 0;
#pragma unroll
        for (int ti = 0; ti < 5; ++ti)
#pragma unroll
            for (int tj = ti; tj < 5; ++tj) {
                acc[idx] = __builtin_amdgcn_mfma_f32_16x16x32_bf16(
                    fr[ti].b, fr[tj].b, acc[idx], 0, 0, 0);
                ++idx;
            }
    }

    __syncthreads();   // Gs zero-init complete across all waves

    // wave accs -> LDS (C/D layout: col = lane&15, row = quad*4 + reg)
    {
        int idx = 0;
#pragma unroll
        for (int ti = 0; ti < 5; ++ti)
#pragma unroll
            for (int tj = ti; tj < 5; ++tj) {
#pragma unroll
                for (int r = 0; r < 4; ++r) {
                    int row = 16 * ti + quad * 4 + r;
                    int col = 16 * tj + m;
                    atomicAdd(&Gs[row * NC + col], acc[idx][r]);
                }
                ++idx;
            }
    }
    __syncthreads();

    // block partial -> global (upper-triangle tiles only; 15 atomics/thread).
    // Measured R0/R1: this is cheaper than a partial-buffer + reduce pass.
    {
        int r  = tid >> 4;
        int cl = tid & 15;
#pragma unroll
        for (int ti = 0; ti < 5; ++ti)
#pragma unroll
            for (int tj = ti; tj < 5; ++tj) {
                int row = 16 * ti + r, col = 16 * tj + cl;
                atomicAdd(&G[row * NC + col], Gs[row * NC + col]);
            }
    }
}

// Stage 2: target = cooc/(count+eps) + eye ; smooth-L1-ish ; mean -> out[0]
__global__ __launch_bounds__(256) void loss_kernel(const float* __restrict__ pre_adj,
                                                   const float* __restrict__ G,
                                                   float* __restrict__ out) {
    const int tid = threadIdx.x;
    float sum = 0.f;
    for (int u = tid; u < NC * NC; u += 256) {
        int i = u / NC, j = u - i * NC;
        float target;
        if (i == j) {
            target = 1.0f;
        } else {
            // G stored only for tile(i) <= tile(j); G is symmetric
            float num = ((i >> 4) <= (j >> 4)) ? G[i * NC + j] : G[j * NC + i];
            float cnt = G[i * NC + i];            // count[i] = diag (binary labels)
            target = num / (cnt + 1e-7f);
        }
        float r = fabsf(pre_adj[u] - target);
        sum += (r < 1.0f) ? r * r : (r - 0.5f);
    }
    // wave reduce (64 lanes) then cross-wave via LDS
#pragma unroll
    for (int off = 32; off > 0; off >>= 1) sum += __shfl_down(sum, off);
    __shared__ float ws[4];
    if ((tid & 63) == 0) ws[tid >> 6] = sum;
    __syncthreads();
    if (tid == 0) out[0] = (ws[0] + ws[1] + ws[2] + ws[3]) * (1.0f / 6400.0f);
}

extern "C" void kernel_launch(void* const* d_in, const int* in_sizes, int n_in,
                              void* d_out, int out_size, void* d_ws, size_t ws_size,
                              hipStream_t stream) {
    const float* pre_adj = (const float*)d_in[0];   // [80,80]
    const float* label   = (const float*)d_in[1];   // [1048576,80]
    float* out = (float*)d_out;                     // scalar
    float* G   = (float*)d_ws;                      // 80*80 fp32 accumulator

    hipMemsetAsync(G, 0, NC * NC * sizeof(float), stream);
    gram_kernel<<<NBLK, NTHR, 0, stream>>>(label, G);
    loss_kernel<<<1, 256, 0, stream>>>(pre_adj, G, out);
}